// Round 1
// baseline (1199.261 us; speedup 1.0000x reference)
//
#include <hip/hip_runtime.h>

#define Bdim 32
#define Tdim 128
#define Zdim 100
#define Sdim 6
#define Hdim 64
#define ZB   3200           // Z*B
#define F1   512
#define F2   128
#define Mrows (ZB * Tdim)   // 409600

typedef _Float16 f16x8 __attribute__((ext_vector_type(8)));
typedef float f32x4 __attribute__((ext_vector_type(4)));

__device__ __forceinline__ float sigmoidf_fast(float x) {
  return 1.f / (1.f + __expf(-x));
}
__device__ __forceinline__ float tanhf_fast(float x) {
  // tanh(x) = 1 - 2/(e^{2x}+1); stable at both extremes with __expf
  return 1.f - 2.f / (__expf(2.f * x) + 1.f);
}

// ---------------------------------------------------------------- prep: fp32->fp16 weights
__global__ __launch_bounds__(256) void prep_kernel(
    const float* __restrict__ w1, const float* __restrict__ w2,
    _Float16* __restrict__ w1f, _Float16* __restrict__ w2f) {
  int i = blockIdx.x * 256 + threadIdx.x;      // grid covers 65536
  if (i < F1 * Hdim) w1f[i] = (_Float16)w1[i];
  if (i < F2 * F1)  w2f[i] = (_Float16)w2[i];
}

// ---------------------------------------------------------------- GRU (fused input proj)
// 1 wave = 4 rows, lane = hidden dim. W_hh in LDS [k][g] (2-way banks = free).
// h broadcast via v_readlane (VALU pipe), gi computed on the fly from x.
__global__ __launch_bounds__(256) void gru_kernel(
    const float* __restrict__ x, const float* __restrict__ W_ih,
    const float* __restrict__ W_hh, const float* __restrict__ b_ih,
    const float* __restrict__ b_hh, _Float16* __restrict__ sx) {
  __shared__ float whh[Hdim * 192];
  const int tid = threadIdx.x;
  const int lane = tid & 63;
  const int wave = tid >> 6;

  for (int idx = tid; idx < Hdim * 192; idx += 256) {
    int k = idx / 192, g = idx - k * 192;
    whh[idx] = W_hh[g * Hdim + k];            // whh[k*192+g] = W_hh[g][k]
  }
  __syncthreads();

  float wih[3][Sdim], bih[3], bhh[3];
#pragma unroll
  for (int gg = 0; gg < 3; gg++) {
    int g = gg * 64 + lane;
#pragma unroll
    for (int s = 0; s < Sdim; s++) wih[gg][s] = W_ih[g * Sdim + s];
    bih[gg] = b_ih[g];
    bhh[gg] = b_hh[g];
  }

  const int row0 = blockIdx.x * 16 + wave * 4;
  const float* xptr[4];
  _Float16* sxp[4];
#pragma unroll
  for (int r = 0; r < 4; r++) {
    int n = row0 + r;                         // n = z*B + b
    int z = n >> 5;                           // /32
    int b = n & 31;
    xptr[r] = x + (size_t)b * (Tdim * Zdim * Sdim) + (size_t)z * Sdim;
    sxp[r] = sx + (size_t)n * Tdim * Hdim + lane;
  }

  float h[4] = {0.f, 0.f, 0.f, 0.f};
  for (int t = 0; t < Tdim; t++) {
    const int toff = t * (Zdim * Sdim);
    // fused gi = x @ W_ih.T + b_ih (wave-uniform x loads, hidden behind k-loop)
    float gi[4][3];
#pragma unroll
    for (int r = 0; r < 4; r++) {
      float xv[Sdim];
#pragma unroll
      for (int s = 0; s < Sdim; s++) xv[s] = xptr[r][toff + s];
#pragma unroll
      for (int gg = 0; gg < 3; gg++) {
        float a = bih[gg];
#pragma unroll
        for (int s = 0; s < Sdim; s++) a = fmaf(xv[s], wih[gg][s], a);
        gi[r][gg] = a;
      }
    }
    float acc[4][3];
#pragma unroll
    for (int r = 0; r < 4; r++)
#pragma unroll
      for (int gg = 0; gg < 3; gg++) acc[r][gg] = bhh[gg];

#pragma unroll 16
    for (int k = 0; k < 64; k++) {
      float wr = whh[k * 192 + lane];
      float wz = whh[k * 192 + 64 + lane];
      float wn = whh[k * 192 + 128 + lane];
#pragma unroll
      for (int r = 0; r < 4; r++) {
        float hk = __int_as_float(__builtin_amdgcn_readlane(__float_as_int(h[r]), k));
        acc[r][0] = fmaf(wr, hk, acc[r][0]);
        acc[r][1] = fmaf(wz, hk, acc[r][1]);
        acc[r][2] = fmaf(wn, hk, acc[r][2]);
      }
    }
#pragma unroll
    for (int r = 0; r < 4; r++) {
      float rr = sigmoidf_fast(gi[r][0] + acc[r][0]);
      float zz = sigmoidf_fast(gi[r][1] + acc[r][1]);
      float nn = tanhf_fast(gi[r][2] + rr * acc[r][2]);
      h[r] = fmaf(zz, h[r] - nn, nn);         // (1-z)*n + z*h
      sxp[r][t * Hdim] = (_Float16)h[r];
    }
  }
}

// ---------------------------------------------------------------- fused MLP (MFMA fp16)
// block = 64 rows, wave = 16 rows. a1 lives only in LDS; a2/out only in regs.
__global__ __launch_bounds__(256) void mlp_kernel(
    const _Float16* __restrict__ sx, const _Float16* __restrict__ w1f,
    const _Float16* __restrict__ w2f, const float* __restrict__ b1,
    const float* __restrict__ b2, const float* __restrict__ w3,
    const float* __restrict__ b3, float* __restrict__ out) {
  __shared__ _Float16 a1s[64 * F1];           // 64 KB, stride 512 f16
  const int tid = threadIdx.x;
  const int lane = tid & 63;
  const int wave = tid >> 6;
  const int c = lane & 15;                    // free-dim index (m for A, n for B/D-col)
  const int q = lane >> 4;                    // quad
  const size_t m0 = (size_t)blockIdx.x * 64;
  const int mw = wave * 16;

  // ---- layer 1: (16x64) @ (64x512)
  f16x8 A0, A1;
  {
    const _Float16* ap = sx + (m0 + mw + c) * Hdim + q * 8;
    A0 = *(const f16x8*)(ap);
    A1 = *(const f16x8*)(ap + 32);
  }
#pragma unroll 4
  for (int nt = 0; nt < 32; nt++) {
    const int n = nt * 16 + c;
    const _Float16* bp = w1f + n * Hdim + q * 8;   // B[k][n] = w1[n][k]
    f16x8 B0 = *(const f16x8*)(bp);
    f16x8 B1 = *(const f16x8*)(bp + 32);
    f32x4 acc = {0.f, 0.f, 0.f, 0.f};
    acc = __builtin_amdgcn_mfma_f32_16x16x32_f16(A0, B0, acc, 0, 0, 0);
    acc = __builtin_amdgcn_mfma_f32_16x16x32_f16(A1, B1, acc, 0, 0, 0);
    const float bias = b1[n];
#pragma unroll
    for (int r = 0; r < 4; r++) {             // C: col=c(=n), row=q*4+r
      float v = acc[r] + bias;
      v = v > 0.f ? v : 0.f;
      a1s[(mw + q * 4 + r) * F1 + n] = (_Float16)v;
    }
  }
  __syncthreads();

  // ---- layer 2: (16x512) @ (512x128)
  f32x4 acc2[8];
#pragma unroll
  for (int i = 0; i < 8; i++) acc2[i] = (f32x4){0.f, 0.f, 0.f, 0.f};
#pragma unroll 2
  for (int kt = 0; kt < 16; kt++) {
    const _Float16* ap = a1s + (mw + c) * F1 + kt * 32 + q * 8;
    f16x8 A = *(const f16x8*)(ap);
#pragma unroll
    for (int nt = 0; nt < 8; nt++) {
      const int n = nt * 16 + c;
      f16x8 Bf = *(const f16x8*)(w2f + n * F1 + kt * 32 + q * 8);
      acc2[nt] = __builtin_amdgcn_mfma_f32_16x16x32_f16(A, Bf, acc2[nt], 0, 0, 0);
    }
  }

  // ---- layer 3: out[row] = sum_n relu(a2)*w3[n] + b3, reduced from C-frags
  float part[4] = {0.f, 0.f, 0.f, 0.f};
#pragma unroll
  for (int nt = 0; nt < 8; nt++) {
    const int n = nt * 16 + c;
    const float bias = b2[n];
    const float w3v = w3[n];
#pragma unroll
    for (int r = 0; r < 4; r++) {
      float v = acc2[nt][r] + bias;
      v = v > 0.f ? v : 0.f;
      part[r] = fmaf(v, w3v, part[r]);
    }
  }
#pragma unroll
  for (int off = 1; off < 16; off <<= 1) {
#pragma unroll
    for (int r = 0; r < 4; r++) part[r] += __shfl_xor(part[r], off, 64);
  }
  if (c == 0) {
    f32x4 res;
#pragma unroll
    for (int r = 0; r < 4; r++) res[r] = part[r] + b3[0];
    *(f32x4*)(out + m0 + mw + q * 4) = res;   // rows q*4..q*4+3, 16B aligned
  }
}

// ----------------------------------------------------------------
extern "C" void kernel_launch(void* const* d_in, const int* in_sizes, int n_in,
                              void* d_out, int out_size, void* d_ws, size_t ws_size,
                              hipStream_t stream) {
  const float* x    = (const float*)d_in[0];
  const float* W_ih = (const float*)d_in[1];
  const float* W_hh = (const float*)d_in[2];
  const float* b_ih = (const float*)d_in[3];
  const float* b_hh = (const float*)d_in[4];
  const float* w1   = (const float*)d_in[5];
  const float* b1   = (const float*)d_in[6];
  const float* w2   = (const float*)d_in[7];
  const float* b2   = (const float*)d_in[8];
  const float* w3   = (const float*)d_in[9];
  const float* b3   = (const float*)d_in[10];
  float* out = (float*)d_out;

  char* ws = (char*)d_ws;
  _Float16* sxf = (_Float16*)ws;                                    // 52.4 MB
  _Float16* w1f = (_Float16*)(ws + (size_t)Mrows * Hdim * 2);       // 64 KB
  _Float16* w2f = (_Float16*)(ws + (size_t)Mrows * Hdim * 2 + (size_t)F1 * Hdim * 2);

  hipLaunchKernelGGL(prep_kernel, dim3(256), dim3(256), 0, stream, w1, w2, w1f, w2f);
  hipLaunchKernelGGL(gru_kernel, dim3(ZB / 16), dim3(256), 0, stream,
                     x, W_ih, W_hh, b_ih, b_hh, sxf);
  hipLaunchKernelGGL(mlp_kernel, dim3(Mrows / 64), dim3(256), 0, stream,
                     sxf, w1f, w2f, b1, b2, w3, b3, out);
}

// Round 2
// 788.508 us; speedup vs baseline: 1.5209x; 1.5209x over previous
//
#include <hip/hip_runtime.h>

#define Tdim 128
#define Zdim 100
#define Sdim 6
#define Hdim 64
#define ZB   3200           // Z*B
#define F1   512
#define F2   128
#define Mrows (ZB * Tdim)   // 409600

typedef _Float16 f16x8 __attribute__((ext_vector_type(8)));
typedef _Float16 f16x4 __attribute__((ext_vector_type(4)));
typedef float f32x4 __attribute__((ext_vector_type(4)));

__device__ __forceinline__ float sigmoidf_fast(float x) {
  return 1.f / (1.f + __expf(-x));
}
__device__ __forceinline__ float tanhf_fast(float x) {
  return 1.f - 2.f / (__expf(2.f * x) + 1.f);
}

// ---------------------------------------------------------------- prep: fp32->fp16 weights
__global__ __launch_bounds__(256) void prep_kernel(
    const float* __restrict__ w1, const float* __restrict__ w2,
    _Float16* __restrict__ w1f, _Float16* __restrict__ w2f) {
  int i = blockIdx.x * 256 + threadIdx.x;      // grid covers 65536
  if (i < F1 * Hdim) w1f[i] = (_Float16)w1[i];
  if (i < F2 * F1)  w2f[i] = (_Float16)w2[i];
}

// ---------------------------------------------------------------- GRU
// 2 rows/wave (1600 waves, 1.56/SIMD). r,z hidden weights in VGPRs (128),
// n-gate weights via LDS [g][65] (2-way bank alias = free). h broadcast via
// readlane. x prefetched one step ahead. fp32 math throughout the recurrence.
__global__ __launch_bounds__(256, 2) void gru_kernel(
    const float* __restrict__ x, const float* __restrict__ W_ih,
    const float* __restrict__ W_hh, const float* __restrict__ b_ih,
    const float* __restrict__ b_hh, _Float16* __restrict__ sx) {
  __shared__ float whn[64 * 65];
  const int tid = threadIdx.x;
  const int lane = tid & 63;
  const int wave = tid >> 6;

  for (int idx = tid; idx < 64 * 64; idx += 256) {
    int g = idx >> 6, k = idx & 63;
    whn[g * 65 + k] = W_hh[(128 + g) * 64 + k];
  }
  __syncthreads();

  float wr[64], wz[64];
  {
    const float* pr = W_hh + lane * 64;        // r-gate row (gate = lane)
    const float* pz = W_hh + (64 + lane) * 64; // z-gate row
#pragma unroll
    for (int kb = 0; kb < 16; kb++) {
      f32x4 a = *(const f32x4*)(pr + kb * 4);
      f32x4 b = *(const f32x4*)(pz + kb * 4);
      wr[kb * 4 + 0] = a[0]; wr[kb * 4 + 1] = a[1];
      wr[kb * 4 + 2] = a[2]; wr[kb * 4 + 3] = a[3];
      wz[kb * 4 + 0] = b[0]; wz[kb * 4 + 1] = b[1];
      wz[kb * 4 + 2] = b[2]; wz[kb * 4 + 3] = b[3];
    }
  }
  float wihr[Sdim], wihz[Sdim], wihn[Sdim];
#pragma unroll
  for (int s = 0; s < Sdim; s++) {
    wihr[s] = W_ih[lane * Sdim + s];
    wihz[s] = W_ih[(64 + lane) * Sdim + s];
    wihn[s] = W_ih[(128 + lane) * Sdim + s];
  }
  const float bihr = b_ih[lane], bihz = b_ih[64 + lane], bihn = b_ih[128 + lane];
  const float bhhr = b_hh[lane], bhhz = b_hh[64 + lane], bhhn = b_hh[128 + lane];

  const int row0 = blockIdx.x * 8 + wave * 2;
  const float* xp[2];
  _Float16* sxp[2];
#pragma unroll
  for (int r = 0; r < 2; r++) {
    int n = row0 + r;                          // n = z*B + b
    int z = n >> 5;
    int b = n & 31;
    xp[r] = x + (size_t)b * (Tdim * Zdim * Sdim) + (size_t)z * Sdim;
    sxp[r] = sx + (size_t)n * Tdim * Hdim + lane;
  }

  float h[2] = {0.f, 0.f};
  float xv[2][Sdim];
#pragma unroll
  for (int r = 0; r < 2; r++)
#pragma unroll
    for (int s = 0; s < Sdim; s++) xv[r][s] = xp[r][s];

  for (int t = 0; t < Tdim; t++) {
    // input projection from current xv
    float gr[2], gz[2], gn[2];
#pragma unroll
    for (int r = 0; r < 2; r++) {
      float a0 = bihr, a1 = bihz, a2 = bihn;
#pragma unroll
      for (int s = 0; s < Sdim; s++) {
        a0 = fmaf(xv[r][s], wihr[s], a0);
        a1 = fmaf(xv[r][s], wihz[s], a1);
        a2 = fmaf(xv[r][s], wihn[s], a2);
      }
      gr[r] = a0; gz[r] = a1; gn[r] = a2;
    }
    // prefetch next timestep's x (consumed next iteration)
    if (t + 1 < Tdim) {
#pragma unroll
      for (int r = 0; r < 2; r++) {
        const float* p = xp[r] + (size_t)(t + 1) * (Zdim * Sdim);
#pragma unroll
        for (int s = 0; s < Sdim; s++) xv[r][s] = p[s];
      }
    }
    float ar[2] = {bhhr, bhhr}, az[2] = {bhhz, bhhz}, an[2] = {bhhn, bhhn};
#pragma unroll
    for (int k = 0; k < 64; k++) {
      float wnv = whn[lane * 65 + k];
#pragma unroll
      for (int r = 0; r < 2; r++) {
        float hk = __int_as_float(__builtin_amdgcn_readlane(__float_as_int(h[r]), k));
        ar[r] = fmaf(wr[k], hk, ar[r]);
        az[r] = fmaf(wz[k], hk, az[r]);
        an[r] = fmaf(wnv, hk, an[r]);
      }
    }
#pragma unroll
    for (int r = 0; r < 2; r++) {
      float rr = sigmoidf_fast(gr[r] + ar[r]);
      float zz = sigmoidf_fast(gz[r] + az[r]);
      float nn = tanhf_fast(gn[r] + rr * an[r]);
      h[r] = fmaf(zz, h[r] - nn, nn);          // (1-z)*n + z*h
      sxp[r][t * Hdim] = (_Float16)h[r];
    }
  }
}

// ---------------------------------------------------------------- fused MLP (transposed MFMA)
// Per wave: 32 rows (2 groups of 16). layer1/layer2 computed transposed:
// D = W @ actT, so lane col index = batch row. a1 exists only as a 32-wide
// k-chunk in a tiny per-wave LDS buffer (C-layout -> B-layout transform).
// No __syncthreads in the hot path; layer3 reduced in-register.
__global__ __launch_bounds__(256) void mlp_kernel(
    const _Float16* __restrict__ sx, const _Float16* __restrict__ w1f,
    const _Float16* __restrict__ w2f, const float* __restrict__ b1,
    const float* __restrict__ b2, const float* __restrict__ w3,
    const float* __restrict__ b3, float* __restrict__ out) {
  // [wave][buf][group][row 16][k 32 + pad4] fp16 ; stride 36 -> ~2-way banks
  __shared__ _Float16 lds[4][2][2][16][36];
  const int tid = threadIdx.x;
  const int lane = tid & 63;
  const int wave = tid >> 6;
  const int c = lane & 15;
  const int q = lane >> 4;
  const size_t m0 = ((size_t)blockIdx.x * 4 + wave) * 32;

  // sx B-frags: B[k=h][n=row], K=64 -> 2 ktiles per group
  f16x8 Bs[2][2];
#pragma unroll
  for (int g = 0; g < 2; g++)
#pragma unroll
    for (int kk = 0; kk < 2; kk++)
      Bs[g][kk] = *(const f16x8*)(sx + (m0 + g * 16 + c) * Hdim + kk * 32 + q * 8);

  f32x4 acc2[2][8];
#pragma unroll
  for (int g = 0; g < 2; g++)
#pragma unroll
    for (int nt = 0; nt < 8; nt++) acc2[g][nt] = (f32x4){0.f, 0.f, 0.f, 0.f};

  for (int kt = 0; kt < 16; kt++) {
    const int buf = kt & 1;
    // ---- layer1 for f1-chunk [kt*32, kt*32+32): two 16-wide m-tiles
#pragma unroll
    for (int ntl = 0; ntl < 2; ntl++) {
      const int f1b = kt * 32 + ntl * 16;
      const _Float16* wp = w1f + (size_t)(f1b + c) * Hdim + q * 8;
      f16x8 A0 = *(const f16x8*)(wp);
      f16x8 A1 = *(const f16x8*)(wp + 32);
      f32x4 bb = *(const f32x4*)(b1 + f1b + q * 4);
#pragma unroll
      for (int g = 0; g < 2; g++) {
        f32x4 cc = {0.f, 0.f, 0.f, 0.f};
        cc = __builtin_amdgcn_mfma_f32_16x16x32_f16(A0, Bs[g][0], cc, 0, 0, 0);
        cc = __builtin_amdgcn_mfma_f32_16x16x32_f16(A1, Bs[g][1], cc, 0, 0, 0);
        // D[m=f1_local=q*4+r][n=row=c]: bias+relu, pack, one b64 LDS write
        f16x4 pk;
#pragma unroll
        for (int r = 0; r < 4; r++) {
          float v = cc[r] + bb[r];
          pk[r] = (_Float16)(v > 0.f ? v : 0.f);
        }
        *(f16x4*)(&lds[wave][buf][g][c][ntl * 16 + q * 4]) = pk;
      }
    }
    // ---- read back as B-frags: B[k=f1_local=q*8+j][n=row=c]
    f16x8 Ba[2];
#pragma unroll
    for (int g = 0; g < 2; g++) {
      f16x4 lo = *(const f16x4*)(&lds[wave][buf][g][c][q * 8]);
      f16x4 hi = *(const f16x4*)(&lds[wave][buf][g][c][q * 8 + 4]);
#pragma unroll
      for (int j = 0; j < 4; j++) { Ba[g][j] = lo[j]; Ba[g][4 + j] = hi[j]; }
    }
    // ---- layer2 partial: A = w2 frags for this k-chunk
#pragma unroll
    for (int nt = 0; nt < 8; nt++) {
      f16x8 A2 = *(const f16x8*)(w2f + (size_t)(nt * 16 + c) * F1 + kt * 32 + q * 8);
#pragma unroll
      for (int g = 0; g < 2; g++)
        acc2[g][nt] = __builtin_amdgcn_mfma_f32_16x16x32_f16(A2, Ba[g], acc2[g][nt], 0, 0, 0);
    }
  }

  // ---- layer3: out[row] = sum_f2 relu(a2+b2)*w3 + b3
  float part[2] = {0.f, 0.f};
#pragma unroll
  for (int nt = 0; nt < 8; nt++) {
    f32x4 bb = *(const f32x4*)(b2 + nt * 16 + q * 4);
    f32x4 ww = *(const f32x4*)(w3 + nt * 16 + q * 4);
#pragma unroll
    for (int g = 0; g < 2; g++) {
#pragma unroll
      for (int r = 0; r < 4; r++) {
        float v = acc2[g][nt][r] + bb[r];
        v = v > 0.f ? v : 0.f;
        part[g] = fmaf(v, ww[r], part[g]);
      }
    }
  }
#pragma unroll
  for (int g = 0; g < 2; g++) {
    part[g] += __shfl_xor(part[g], 16, 64);
    part[g] += __shfl_xor(part[g], 32, 64);
  }
  if (q < 2) {
    float pv = (q == 0) ? part[0] : part[1];
    out[m0 + q * 16 + c] = pv + b3[0];
  }
}

// ----------------------------------------------------------------
extern "C" void kernel_launch(void* const* d_in, const int* in_sizes, int n_in,
                              void* d_out, int out_size, void* d_ws, size_t ws_size,
                              hipStream_t stream) {
  const float* x    = (const float*)d_in[0];
  const float* W_ih = (const float*)d_in[1];
  const float* W_hh = (const float*)d_in[2];
  const float* b_ih = (const float*)d_in[3];
  const float* b_hh = (const float*)d_in[4];
  const float* w1   = (const float*)d_in[5];
  const float* b1   = (const float*)d_in[6];
  const float* w2   = (const float*)d_in[7];
  const float* b2   = (const float*)d_in[8];
  const float* w3   = (const float*)d_in[9];
  const float* b3   = (const float*)d_in[10];
  float* out = (float*)d_out;

  char* ws = (char*)d_ws;
  _Float16* sxf = (_Float16*)ws;                                    // 52.4 MB
  _Float16* w1f = (_Float16*)(ws + (size_t)Mrows * Hdim * 2);       // 64 KB
  _Float16* w2f = (_Float16*)(ws + (size_t)Mrows * Hdim * 2 + (size_t)F1 * Hdim * 2);

  hipLaunchKernelGGL(prep_kernel, dim3(256), dim3(256), 0, stream, w1, w2, w1f, w2f);
  hipLaunchKernelGGL(gru_kernel, dim3(ZB / 8), dim3(256), 0, stream,
                     x, W_ih, W_hh, b_ih, b_hh, sxf);
  hipLaunchKernelGGL(mlp_kernel, dim3(Mrows / 128), dim3(256), 0, stream,
                     sxf, w1f, w2f, b1, b2, w3, b3, out);
}

// Round 3
// 419.968 us; speedup vs baseline: 2.8556x; 1.8775x over previous
//
#include <hip/hip_runtime.h>
#include <stdint.h>

#define Tdim 128
#define Zdim 100
#define Sdim 6
#define Hdim 64
#define ZB   3200           // Z*B
#define F1   512
#define F2   128
#define Mrows (ZB * Tdim)   // 409600

typedef _Float16 f16x8 __attribute__((ext_vector_type(8)));
typedef _Float16 f16x4 __attribute__((ext_vector_type(4)));
typedef float f32x4 __attribute__((ext_vector_type(4)));
typedef uint32_t u32x4 __attribute__((ext_vector_type(4)));

__device__ __forceinline__ float sigmoidf_fast(float x) {
  return 1.f / (1.f + __expf(-x));
}
__device__ __forceinline__ float tanhf_fast(float x) {
  return 1.f - 2.f / (__expf(2.f * x) + 1.f);
}

// ---------------------------------------------------------------- prep
// Wf[192][96] fp16: [W_hh | W_ih | 0] row-major per gate (K=96 fused).
// w1p[16][32][72] fp16: per-kt chunk of w1 rows, h-dim padded 64->72.
// w2p[16][128][40] fp16: per-kt k-chunk of w2 (k-major chunks), padded 32->40.
__global__ __launch_bounds__(256) void prep_kernel(
    const float* __restrict__ W_ih, const float* __restrict__ W_hh,
    const float* __restrict__ w1, const float* __restrict__ w2,
    _Float16* __restrict__ Wf, _Float16* __restrict__ w1p,
    _Float16* __restrict__ w2p) {
  int i = blockIdx.x * 256 + threadIdx.x;     // grid covers 137216 exactly
  if (i < 192 * 96) {
    int g = i / 96, k = i - g * 96;
    float v = (k < 64) ? W_hh[g * 64 + k] : ((k < 70) ? W_ih[g * 6 + (k - 64)] : 0.f);
    Wf[i] = (_Float16)v;
  }
  int j = i - 192 * 96;
  if (j >= 0 && j < 16 * 32 * 72) {
    int kt = j / 2304, r = j - kt * 2304;
    int f1 = r / 72, h = r - f1 * 72;
    w1p[j] = (_Float16)((h < 64) ? w1[(kt * 32 + f1) * 64 + h] : 0.f);
  }
  int l = j - 16 * 32 * 72;
  if (l >= 0 && l < 16 * 128 * 40) {
    int kt = l / 5120, r = l - kt * 5120;
    int f2 = r / 40, k = r - f2 * 40;
    w2p[l] = (_Float16)((k < 32) ? w2[f2 * 512 + kt * 32 + k] : 0.f);
  }
}

// ---------------------------------------------------------------- GRU via MFMA
// 1 wave/block, 16 rows/wave, 200 blocks (all co-resident, no tail).
// D = Wf @ [h;x]^T per step: 12 m-tiles of gates, rows are the MFMA n-dim.
// h state lives in D-layout fp32 regs; repacked to B-frags (fp16) via a
// wave-private LDS round-trip each step. Weights live in 144 VGPRs of A-frags.
__global__ __launch_bounds__(64, 1) void gru_kernel(
    const float* __restrict__ x, const _Float16* __restrict__ Wf,
    const float* __restrict__ b_ih, const float* __restrict__ b_hh,
    _Float16* __restrict__ sx) {
  __shared__ _Float16 h16[16][72];            // 2.3 KB, wave-private
  const int lane = threadIdx.x;
  const int c = lane & 15;                    // MFMA col = row index
  const int q = lane >> 4;                    // quad
  const int m0 = blockIdx.x * 16;

  // A-frags: A[m=gate][k], lane holds A[mt*16+c][kt*32+q*8+j]
  f16x8 Arz[8][3], Agh[4][2], Agi[4];
#pragma unroll
  for (int mt = 0; mt < 8; mt++)
#pragma unroll
    for (int kt = 0; kt < 3; kt++)
      Arz[mt][kt] = *(const f16x8*)(Wf + (size_t)(mt * 16 + c) * 96 + kt * 32 + q * 8);
#pragma unroll
  for (int mt = 0; mt < 4; mt++) {
#pragma unroll
    for (int kt = 0; kt < 2; kt++)
      Agh[mt][kt] = *(const f16x8*)(Wf + (size_t)(128 + mt * 16 + c) * 96 + kt * 32 + q * 8);
    Agi[mt] = *(const f16x8*)(Wf + (size_t)(128 + mt * 16 + c) * 96 + 64 + q * 8);
  }
  // biases in D-layout (gate = mt*16 + q*4 + r)
  f32x4 Crz[8], Cgh[4], Cgi[4];
#pragma unroll
  for (int mt = 0; mt < 8; mt++) {
    f32x4 bi = *(const f32x4*)(b_ih + mt * 16 + q * 4);
    f32x4 bh = *(const f32x4*)(b_hh + mt * 16 + q * 4);
#pragma unroll
    for (int r = 0; r < 4; r++) Crz[mt][r] = bi[r] + bh[r];
  }
#pragma unroll
  for (int mt = 0; mt < 4; mt++) {
    Cgh[mt] = *(const f32x4*)(b_hh + 128 + mt * 16 + q * 4);
    Cgi[mt] = *(const f32x4*)(b_ih + 128 + mt * 16 + q * 4);
  }

  const int n = m0 + c;                       // n = z*32 + b
  const int zz = n >> 5, bb = n & 31;
  const float* xp = x + (size_t)bb * (Tdim * Zdim * Sdim) + (size_t)zz * Sdim;
  _Float16* sxp = sx + (size_t)n * Tdim * Hdim;

  float xv[Sdim];
  if (q == 0) {
#pragma unroll
    for (int s = 0; s < Sdim; s++) xv[s] = xp[s];
  }

  f16x8 Bh0 = {0, 0, 0, 0, 0, 0, 0, 0};
  f16x8 Bh1 = {0, 0, 0, 0, 0, 0, 0, 0};
  float hD[16];
#pragma unroll
  for (int i = 0; i < 16; i++) hD[i] = 0.f;

  for (int t = 0; t < Tdim; t++) {
    // B-frag for x: k' 0..5 on q==0 lanes, zero elsewhere
    f16x8 Bx = {0, 0, 0, 0, 0, 0, 0, 0};
    if (q == 0) {
      Bx[0] = (_Float16)xv[0]; Bx[1] = (_Float16)xv[1]; Bx[2] = (_Float16)xv[2];
      Bx[3] = (_Float16)xv[3]; Bx[4] = (_Float16)xv[4]; Bx[5] = (_Float16)xv[5];
    }
    f32x4 Drz[8], Dgh[4], Dgi[4];
#pragma unroll
    for (int mt = 0; mt < 8; mt++) {
      f32x4 a = __builtin_amdgcn_mfma_f32_16x16x32_f16(Arz[mt][0], Bh0, Crz[mt], 0, 0, 0);
      a = __builtin_amdgcn_mfma_f32_16x16x32_f16(Arz[mt][1], Bh1, a, 0, 0, 0);
      Drz[mt] = __builtin_amdgcn_mfma_f32_16x16x32_f16(Arz[mt][2], Bx, a, 0, 0, 0);
    }
#pragma unroll
    for (int mt = 0; mt < 4; mt++) {
      f32x4 a = __builtin_amdgcn_mfma_f32_16x16x32_f16(Agh[mt][0], Bh0, Cgh[mt], 0, 0, 0);
      Dgh[mt] = __builtin_amdgcn_mfma_f32_16x16x32_f16(Agh[mt][1], Bh1, a, 0, 0, 0);
      Dgi[mt] = __builtin_amdgcn_mfma_f32_16x16x32_f16(Agi[mt], Bx, Cgi[mt], 0, 0, 0);
    }
    // prefetch next x while MFMA completes
    if (q == 0 && t + 1 < Tdim) {
      const float* p = xp + (size_t)(t + 1) * (Zdim * Sdim);
#pragma unroll
      for (int s = 0; s < Sdim; s++) xv[s] = p[s];
    }
    // nonlinearity (lane-local: gate g, 64+g, 128+g all live in same lane)
#pragma unroll
    for (int mt = 0; mt < 4; mt++) {
      f16x4 pk;
#pragma unroll
      for (int r = 0; r < 4; r++) {
        float rr = sigmoidf_fast(Drz[mt][r]);
        float zg = sigmoidf_fast(Drz[mt + 4][r]);
        float nn = tanhf_fast(Dgi[mt][r] + rr * Dgh[mt][r]);
        float hnew = nn + zg * (hD[mt * 4 + r] - nn);
        hD[mt * 4 + r] = hnew;
        pk[r] = (_Float16)hnew;
      }
      *(f16x4*)&h16[c][mt * 16 + q * 4] = pk; // hd = mt*16+q*4+r
    }
    // repack D-layout -> B-frags (single wave: no barrier, lgkmcnt only)
    Bh0 = *(const f16x8*)&h16[c][q * 8];
    Bh1 = *(const f16x8*)&h16[c][32 + q * 8];
    // store h_t (already in B layout = sx[row][k])
    *(f16x8*)(sxp + t * 64 + q * 8) = Bh0;
    *(f16x8*)(sxp + t * 64 + 32 + q * 8) = Bh1;
  }
}

// ---------------------------------------------------------------- fused MLP
// Block = 256 thr / 4 waves / 128 rows; per kt the 14.5 KB weight chunk is
// staged once into double-buffered LDS (loads issued one kt ahead), shared by
// all waves. Wave = 32 rows (2 groups of 16), transposed MFMA dataflow.
__global__ __launch_bounds__(256, 2) void mlp_kernel(
    const _Float16* __restrict__ sx, const _Float16* __restrict__ w1p,
    const _Float16* __restrict__ w2p, const float* __restrict__ b1,
    const float* __restrict__ b2, const float* __restrict__ w3,
    const float* __restrict__ b3, float* __restrict__ out) {
  __shared__ __align__(16) _Float16 w1s[2][32][72];   // 2 x 4608 B
  __shared__ __align__(16) _Float16 w2s[2][128][40];  // 2 x 10240 B
  __shared__ __align__(16) _Float16 rep[4][2][2][16][36];
  const int tid = threadIdx.x;
  const int lane = tid & 63;
  const int wave = tid >> 6;
  const int c = lane & 15;
  const int q = lane >> 4;
  const size_t m0 = ((size_t)blockIdx.x * 4 + wave) * 32;

  // activations (rows) as B-frags for the whole kernel
  f16x8 Bs[2][2];
#pragma unroll
  for (int g = 0; g < 2; g++)
#pragma unroll
    for (int kk = 0; kk < 2; kk++)
      Bs[g][kk] = *(const f16x8*)(sx + (m0 + g * 16 + c) * Hdim + kk * 32 + q * 8);

  f32x4 acc2[2][8];
#pragma unroll
  for (int g = 0; g < 2; g++)
#pragma unroll
    for (int nt = 0; nt < 8; nt++) acc2[g][nt] = (f32x4){0.f, 0.f, 0.f, 0.f};

  // stage regs for kt=0
  u32x4 r1a, r1b, r2a, r2b, r2c;
  {
    const u32x4* g1 = (const u32x4*)(w1p);
    const u32x4* g2 = (const u32x4*)(w2p);
    r1a = g1[tid];
    if (tid < 32) r1b = g1[256 + tid];
    r2a = g2[tid];
    r2b = g2[256 + tid];
    if (tid < 128) r2c = g2[512 + tid];
  }

#pragma unroll 2
  for (int kt = 0; kt < 16; kt++) {
    const int buf = kt & 1;
    // commit staged regs -> LDS buf
    {
      u32x4* s1 = (u32x4*)&w1s[buf][0][0];
      u32x4* s2 = (u32x4*)&w2s[buf][0][0];
      s1[tid] = r1a;
      if (tid < 32) s1[256 + tid] = r1b;
      s2[tid] = r2a;
      s2[256 + tid] = r2b;
      if (tid < 128) s2[512 + tid] = r2c;
    }
    // issue loads for kt+1 (overlap with compute below)
    if (kt + 1 < 16) {
      const u32x4* g1 = (const u32x4*)(w1p + (size_t)(kt + 1) * 2304);
      const u32x4* g2 = (const u32x4*)(w2p + (size_t)(kt + 1) * 5120);
      r1a = g1[tid];
      if (tid < 32) r1b = g1[256 + tid];
      r2a = g2[tid];
      r2b = g2[256 + tid];
      if (tid < 128) r2c = g2[512 + tid];
    }
    __syncthreads();

    // ---- layer1: two 16-wide f1 tiles from w1s
#pragma unroll
    for (int ntl = 0; ntl < 2; ntl++) {
      const int f1b = kt * 32 + ntl * 16;
      f16x8 A0 = *(const f16x8*)&w1s[buf][ntl * 16 + c][q * 8];
      f16x8 A1 = *(const f16x8*)&w1s[buf][ntl * 16 + c][32 + q * 8];
      f32x4 bb = *(const f32x4*)(b1 + f1b + q * 4);
#pragma unroll
      for (int g = 0; g < 2; g++) {
        f32x4 cc = {0.f, 0.f, 0.f, 0.f};
        cc = __builtin_amdgcn_mfma_f32_16x16x32_f16(A0, Bs[g][0], cc, 0, 0, 0);
        cc = __builtin_amdgcn_mfma_f32_16x16x32_f16(A1, Bs[g][1], cc, 0, 0, 0);
        f16x4 pk;
#pragma unroll
        for (int r = 0; r < 4; r++) {
          float v = cc[r] + bb[r];
          pk[r] = (_Float16)(v > 0.f ? v : 0.f);
        }
        *(f16x4*)&rep[wave][buf][g][c][ntl * 16 + q * 4] = pk;
      }
    }
    // ---- a1 chunk back as B-frags
    f16x8 Ba[2];
#pragma unroll
    for (int g = 0; g < 2; g++) {
      f16x4 lo = *(const f16x4*)&rep[wave][buf][g][c][q * 8];
      f16x4 hi = *(const f16x4*)&rep[wave][buf][g][c][q * 8 + 4];
#pragma unroll
      for (int j = 0; j < 4; j++) { Ba[g][j] = lo[j]; Ba[g][4 + j] = hi[j]; }
    }
    // ---- layer2 partial from w2s
#pragma unroll
    for (int nt = 0; nt < 8; nt++) {
      f16x8 A2 = *(const f16x8*)&w2s[buf][nt * 16 + c][q * 8];
#pragma unroll
      for (int g = 0; g < 2; g++)
        acc2[g][nt] = __builtin_amdgcn_mfma_f32_16x16x32_f16(A2, Ba[g], acc2[g][nt], 0, 0, 0);
    }
  }

  // ---- layer3: out[row] = sum relu(a2 + b2) * w3 + b3
  float part[2] = {0.f, 0.f};
#pragma unroll
  for (int nt = 0; nt < 8; nt++) {
    f32x4 bb = *(const f32x4*)(b2 + nt * 16 + q * 4);
    f32x4 ww = *(const f32x4*)(w3 + nt * 16 + q * 4);
#pragma unroll
    for (int g = 0; g < 2; g++) {
#pragma unroll
      for (int r = 0; r < 4; r++) {
        float v = acc2[g][nt][r] + bb[r];
        v = v > 0.f ? v : 0.f;
        part[g] = fmaf(v, ww[r], part[g]);
      }
    }
  }
#pragma unroll
  for (int g = 0; g < 2; g++) {
    part[g] += __shfl_xor(part[g], 16, 64);
    part[g] += __shfl_xor(part[g], 32, 64);
  }
  if (q < 2) {
    float pv = (q == 0) ? part[0] : part[1];
    out[m0 + q * 16 + c] = pv + b3[0];
  }
}

// ----------------------------------------------------------------
extern "C" void kernel_launch(void* const* d_in, const int* in_sizes, int n_in,
                              void* d_out, int out_size, void* d_ws, size_t ws_size,
                              hipStream_t stream) {
  const float* x    = (const float*)d_in[0];
  const float* W_ih = (const float*)d_in[1];
  const float* W_hh = (const float*)d_in[2];
  const float* b_ih = (const float*)d_in[3];
  const float* b_hh = (const float*)d_in[4];
  const float* w1   = (const float*)d_in[5];
  const float* b1   = (const float*)d_in[6];
  const float* w2   = (const float*)d_in[7];
  const float* b2   = (const float*)d_in[8];
  const float* w3   = (const float*)d_in[9];
  const float* b3   = (const float*)d_in[10];
  float* out = (float*)d_out;

  char* ws = (char*)d_ws;
  _Float16* sxf = (_Float16*)ws;                          // 52,428,800 B
  _Float16* Wf  = (_Float16*)(ws + 52428800);             // 36,864 B
  _Float16* w1p = (_Float16*)(ws + 52428800 + 36864);     // 73,728 B
  _Float16* w2p = (_Float16*)(ws + 52428800 + 36864 + 73728); // 163,840 B

  hipLaunchKernelGGL(prep_kernel, dim3(536), dim3(256), 0, stream,
                     W_ih, W_hh, w1, w2, Wf, w1p, w2p);
  hipLaunchKernelGGL(gru_kernel, dim3(ZB / 16), dim3(64), 0, stream,
                     x, Wf, b_ih, b_hh, sxf);
  hipLaunchKernelGGL(mlp_kernel, dim3(Mrows / 128), dim3(256), 0, stream,
                     sxf, w1p, w2p, b1, b2, w3, b3, out);
}

// Round 4
// 258.942 us; speedup vs baseline: 4.6314x; 1.6219x over previous
//
#include <hip/hip_runtime.h>
#include <stdint.h>

#define Tdim 128
#define Zdim 100
#define Sdim 6
#define Hdim 64
#define ZB   3200           // Z*B
#define F1   512
#define F2   128
#define Mrows (ZB * Tdim)   // 409600

typedef _Float16 f16x8 __attribute__((ext_vector_type(8)));
typedef _Float16 f16x4 __attribute__((ext_vector_type(4)));
typedef float f32x4 __attribute__((ext_vector_type(4)));
typedef uint32_t u32x4 __attribute__((ext_vector_type(4)));

__device__ __forceinline__ float sigmoidf_fast(float x) {
  return 1.f / (1.f + __expf(-x));
}
__device__ __forceinline__ float tanhf_fast(float x) {
  return 1.f - 2.f / (__expf(2.f * x) + 1.f);
}

// ---------------------------------------------------------------- prep
// Wf[192][96] fp16: [W_hh | W_ih | 0] row-major per gate (K=96 fused).
// w1p[16][32][72] fp16: per-kt chunk of w1 rows, h-dim padded 64->72.
// w2p[16][128][40] fp16: per-kt k-chunk of w2 (k-major chunks), padded 32->40.
__global__ __launch_bounds__(256) void prep_kernel(
    const float* __restrict__ W_ih, const float* __restrict__ W_hh,
    const float* __restrict__ w1, const float* __restrict__ w2,
    _Float16* __restrict__ Wf, _Float16* __restrict__ w1p,
    _Float16* __restrict__ w2p) {
  int i = blockIdx.x * 256 + threadIdx.x;     // grid covers 137216 exactly
  if (i < 192 * 96) {
    int g = i / 96, k = i - g * 96;
    float v = (k < 64) ? W_hh[g * 64 + k] : ((k < 70) ? W_ih[g * 6 + (k - 64)] : 0.f);
    Wf[i] = (_Float16)v;
  }
  int j = i - 192 * 96;
  if (j >= 0 && j < 16 * 32 * 72) {
    int kt = j / 2304, r = j - kt * 2304;
    int f1 = r / 72, h = r - f1 * 72;
    w1p[j] = (_Float16)((h < 64) ? w1[(kt * 32 + f1) * 64 + h] : 0.f);
  }
  int l = j - 16 * 32 * 72;
  if (l >= 0 && l < 16 * 128 * 40) {
    int kt = l / 5120, r = l - kt * 5120;
    int f2 = r / 40, k = r - f2 * 40;
    w2p[l] = (_Float16)((k < 32) ? w2[f2 * 512 + kt * 32 + k] : 0.f);
  }
}

// ---------------------------------------------------------------- GRU via MFMA
// Block = 4 waves, 16 rows. Wave w owns gate-dims [16w,16w+16) of r,z,n:
// 9 MFMA/step, 36 weight VGPRs (no spills). h_prev stays lane-local (the
// same lane computes the same h-dims every step); full h is reassembled
// as B-frags via a double-buffered LDS tile, ONE barrier per step.
__global__ __launch_bounds__(256, 1) void gru_kernel(
    const float* __restrict__ x, const _Float16* __restrict__ Wf,
    const float* __restrict__ b_ih, const float* __restrict__ b_hh,
    _Float16* __restrict__ sx) {
  __shared__ _Float16 h16[2][16][72];         // 4.6 KB double-buffered
  const int tid = threadIdx.x;
  const int lane = tid & 63;
  const int w = tid >> 6;                     // wave id 0..3
  const int c = lane & 15;                    // MFMA col = row index
  const int q = lane >> 4;                    // quad

  const int gr0 = w * 16;                     // r-gate tile base
  const int gz0 = 64 + w * 16;                // z-gate tile base
  const int gn0 = 128 + w * 16;               // n-gate tile base

  // A-frags: A[m=c][k=q*8+j] per 16-gate tile, K=96 fused [h|x|0]
  f16x8 Ar[3], Az[3], Anh[2], Ani;
#pragma unroll
  for (int kf = 0; kf < 3; kf++) {
    Ar[kf] = *(const f16x8*)(Wf + (size_t)(gr0 + c) * 96 + kf * 32 + q * 8);
    Az[kf] = *(const f16x8*)(Wf + (size_t)(gz0 + c) * 96 + kf * 32 + q * 8);
  }
  Anh[0] = *(const f16x8*)(Wf + (size_t)(gn0 + c) * 96 + q * 8);
  Anh[1] = *(const f16x8*)(Wf + (size_t)(gn0 + c) * 96 + 32 + q * 8);
  Ani    = *(const f16x8*)(Wf + (size_t)(gn0 + c) * 96 + 64 + q * 8);

  // biases in D-layout (gate-local m = q*4 + r)
  f32x4 Cr, Cz, Cnh, Cni;
  {
    f32x4 bir = *(const f32x4*)(b_ih + gr0 + q * 4);
    f32x4 bhr = *(const f32x4*)(b_hh + gr0 + q * 4);
    f32x4 biz = *(const f32x4*)(b_ih + gz0 + q * 4);
    f32x4 bhz = *(const f32x4*)(b_hh + gz0 + q * 4);
#pragma unroll
    for (int r = 0; r < 4; r++) { Cr[r] = bir[r] + bhr[r]; Cz[r] = biz[r] + bhz[r]; }
    Cnh = *(const f32x4*)(b_hh + gn0 + q * 4);
    Cni = *(const f32x4*)(b_ih + gn0 + q * 4);
  }

  const int n = blockIdx.x * 16 + c;          // n = z*32 + b
  const int zz = n >> 5, bb = n & 31;
  const float* xp = x + (size_t)bb * (Tdim * Zdim * Sdim) + (size_t)zz * Sdim;
  _Float16* sxp = sx + (size_t)n * Tdim * Hdim;

  float xv[Sdim];
  if (q == 0) {
#pragma unroll
    for (int s = 0; s < Sdim; s++) xv[s] = xp[s];
  }

  f16x8 Bh0 = {0, 0, 0, 0, 0, 0, 0, 0};
  f16x8 Bh1 = {0, 0, 0, 0, 0, 0, 0, 0};
  f32x4 hprev = {0.f, 0.f, 0.f, 0.f};

  for (int t = 0; t < Tdim; t++) {
    f16x8 Bx = {0, 0, 0, 0, 0, 0, 0, 0};
    if (q == 0) {
      Bx[0] = (_Float16)xv[0]; Bx[1] = (_Float16)xv[1]; Bx[2] = (_Float16)xv[2];
      Bx[3] = (_Float16)xv[3]; Bx[4] = (_Float16)xv[4]; Bx[5] = (_Float16)xv[5];
    }
    f32x4 Dr = __builtin_amdgcn_mfma_f32_16x16x32_f16(Ar[0], Bh0, Cr, 0, 0, 0);
    f32x4 Dz = __builtin_amdgcn_mfma_f32_16x16x32_f16(Az[0], Bh0, Cz, 0, 0, 0);
    f32x4 Dnh = __builtin_amdgcn_mfma_f32_16x16x32_f16(Anh[0], Bh0, Cnh, 0, 0, 0);
    f32x4 Dni = __builtin_amdgcn_mfma_f32_16x16x32_f16(Ani, Bx, Cni, 0, 0, 0);
    Dr = __builtin_amdgcn_mfma_f32_16x16x32_f16(Ar[1], Bh1, Dr, 0, 0, 0);
    Dz = __builtin_amdgcn_mfma_f32_16x16x32_f16(Az[1], Bh1, Dz, 0, 0, 0);
    Dnh = __builtin_amdgcn_mfma_f32_16x16x32_f16(Anh[1], Bh1, Dnh, 0, 0, 0);
    Dr = __builtin_amdgcn_mfma_f32_16x16x32_f16(Ar[2], Bx, Dr, 0, 0, 0);
    Dz = __builtin_amdgcn_mfma_f32_16x16x32_f16(Az[2], Bx, Dz, 0, 0, 0);

    // prefetch next x while MFMA completes
    if (q == 0 && t + 1 < Tdim) {
      const float* p = xp + (size_t)(t + 1) * (Zdim * Sdim);
#pragma unroll
      for (int s = 0; s < Sdim; s++) xv[s] = p[s];
    }

    f16x4 pk;
#pragma unroll
    for (int r = 0; r < 4; r++) {
      float rr = sigmoidf_fast(Dr[r]);
      float zg = sigmoidf_fast(Dz[r]);
      float nn = tanhf_fast(Dni[r] + rr * Dnh[r]);
      float hnew = nn + zg * (hprev[r] - nn);
      hprev[r] = hnew;
      pk[r] = (_Float16)hnew;
    }
    *(f16x4*)&h16[t & 1][c][w * 16 + q * 4] = pk;
    *(f16x4*)(sxp + t * Hdim + w * 16 + q * 4) = pk;
    __syncthreads();
    Bh0 = *(const f16x8*)&h16[t & 1][c][q * 8];
    Bh1 = *(const f16x8*)&h16[t & 1][c][32 + q * 8];
  }
}

// ---------------------------------------------------------------- fused MLP
// Block = 4 waves / 128 rows; weight chunk (14.8 KB/kt) staged in
// double-buffered LDS. Order per kt: issue loads(kt+1) -> compute(kt) ->
// commit(kt+1) -> barrier, so the barrier's vmcnt(0) drain lands AFTER the
// loads had the whole compute phase in flight. 3 blocks/CU.
__global__ __launch_bounds__(256, 3) void mlp_kernel(
    const _Float16* __restrict__ sx, const _Float16* __restrict__ w1p,
    const _Float16* __restrict__ w2p, const float* __restrict__ b1,
    const float* __restrict__ b2, const float* __restrict__ w3,
    const float* __restrict__ b3, float* __restrict__ out) {
  __shared__ __align__(16) _Float16 w1s[2][32][72];   // 2 x 4608 B
  __shared__ __align__(16) _Float16 w2s[2][128][40];  // 2 x 10240 B
  __shared__ __align__(16) _Float16 rep[4][2][2][16][36];
  const int tid = threadIdx.x;
  const int lane = tid & 63;
  const int wave = tid >> 6;
  const int c = lane & 15;
  const int q = lane >> 4;
  const size_t m0 = ((size_t)blockIdx.x * 4 + wave) * 32;

  // activations (rows) as B-frags for the whole kernel
  f16x8 Bs[2][2];
#pragma unroll
  for (int g = 0; g < 2; g++)
#pragma unroll
    for (int kk = 0; kk < 2; kk++)
      Bs[g][kk] = *(const f16x8*)(sx + (m0 + g * 16 + c) * Hdim + kk * 32 + q * 8);

  f32x4 acc2[2][8];
#pragma unroll
  for (int g = 0; g < 2; g++)
#pragma unroll
    for (int nt = 0; nt < 8; nt++) acc2[g][nt] = (f32x4){0.f, 0.f, 0.f, 0.f};

  u32x4 r1a, r1b, r2a, r2b, r2c;
  // stage kt=0 and commit before the loop
  {
    const u32x4* g1 = (const u32x4*)(w1p);
    const u32x4* g2 = (const u32x4*)(w2p);
    r1a = g1[tid];
    if (tid < 32) r1b = g1[256 + tid];
    r2a = g2[tid];
    r2b = g2[256 + tid];
    if (tid < 128) r2c = g2[512 + tid];
    u32x4* s1 = (u32x4*)&w1s[0][0][0];
    u32x4* s2 = (u32x4*)&w2s[0][0][0];
    s1[tid] = r1a;
    if (tid < 32) s1[256 + tid] = r1b;
    s2[tid] = r2a;
    s2[256 + tid] = r2b;
    if (tid < 128) s2[512 + tid] = r2c;
  }
  __syncthreads();

#pragma unroll 2
  for (int kt = 0; kt < 16; kt++) {
    const int buf = kt & 1;
    // issue loads for kt+1 (land during compute below)
    if (kt + 1 < 16) {
      const u32x4* g1 = (const u32x4*)(w1p + (size_t)(kt + 1) * 2304);
      const u32x4* g2 = (const u32x4*)(w2p + (size_t)(kt + 1) * 5120);
      r1a = g1[tid];
      if (tid < 32) r1b = g1[256 + tid];
      r2a = g2[tid];
      r2b = g2[256 + tid];
      if (tid < 128) r2c = g2[512 + tid];
    }

    // ---- layer1: two 16-wide f1 tiles from w1s[buf]
#pragma unroll
    for (int ntl = 0; ntl < 2; ntl++) {
      const int f1b = kt * 32 + ntl * 16;
      f16x8 A0 = *(const f16x8*)&w1s[buf][ntl * 16 + c][q * 8];
      f16x8 A1 = *(const f16x8*)&w1s[buf][ntl * 16 + c][32 + q * 8];
      f32x4 bb = *(const f32x4*)(b1 + f1b + q * 4);
#pragma unroll
      for (int g = 0; g < 2; g++) {
        f32x4 cc = {0.f, 0.f, 0.f, 0.f};
        cc = __builtin_amdgcn_mfma_f32_16x16x32_f16(A0, Bs[g][0], cc, 0, 0, 0);
        cc = __builtin_amdgcn_mfma_f32_16x16x32_f16(A1, Bs[g][1], cc, 0, 0, 0);
        f16x4 pk;
#pragma unroll
        for (int r = 0; r < 4; r++) {
          float v = cc[r] + bb[r];
          pk[r] = (_Float16)(v > 0.f ? v : 0.f);
        }
        *(f16x4*)&rep[wave][buf][g][c][ntl * 16 + q * 4] = pk;
      }
    }
    // ---- a1 chunk back as B-frags (wave-private LDS, no barrier)
    f16x8 Ba[2];
#pragma unroll
    for (int g = 0; g < 2; g++) {
      f16x4 lo = *(const f16x4*)&rep[wave][buf][g][c][q * 8];
      f16x4 hi = *(const f16x4*)&rep[wave][buf][g][c][q * 8 + 4];
#pragma unroll
      for (int j = 0; j < 4; j++) { Ba[g][j] = lo[j]; Ba[g][4 + j] = hi[j]; }
    }
    // ---- layer2 partial from w2s[buf]
#pragma unroll
    for (int nt = 0; nt < 8; nt++) {
      f16x8 A2 = *(const f16x8*)&w2s[buf][nt * 16 + c][q * 8];
#pragma unroll
      for (int g = 0; g < 2; g++)
        acc2[g][nt] = __builtin_amdgcn_mfma_f32_16x16x32_f16(A2, Ba[g], acc2[g][nt], 0, 0, 0);
    }

    // ---- commit kt+1 regs -> other LDS buf, then barrier
    if (kt + 1 < 16) {
      u32x4* s1 = (u32x4*)&w1s[buf ^ 1][0][0];
      u32x4* s2 = (u32x4*)&w2s[buf ^ 1][0][0];
      s1[tid] = r1a;
      if (tid < 32) s1[256 + tid] = r1b;
      s2[tid] = r2a;
      s2[256 + tid] = r2b;
      if (tid < 128) s2[512 + tid] = r2c;
      __syncthreads();
    }
  }

  // ---- layer3: out[row] = sum relu(a2 + b2) * w3 + b3
  float part[2] = {0.f, 0.f};
#pragma unroll
  for (int nt = 0; nt < 8; nt++) {
    f32x4 bb = *(const f32x4*)(b2 + nt * 16 + q * 4);
    f32x4 ww = *(const f32x4*)(w3 + nt * 16 + q * 4);
#pragma unroll
    for (int g = 0; g < 2; g++) {
#pragma unroll
      for (int r = 0; r < 4; r++) {
        float v = acc2[g][nt][r] + bb[r];
        v = v > 0.f ? v : 0.f;
        part[g] = fmaf(v, ww[r], part[g]);
      }
    }
  }
#pragma unroll
  for (int g = 0; g < 2; g++) {
    part[g] += __shfl_xor(part[g], 16, 64);
    part[g] += __shfl_xor(part[g], 32, 64);
  }
  if (q < 2) {
    float pv = (q == 0) ? part[0] : part[1];
    out[m0 + q * 16 + c] = pv + b3[0];
  }
}

// ----------------------------------------------------------------
extern "C" void kernel_launch(void* const* d_in, const int* in_sizes, int n_in,
                              void* d_out, int out_size, void* d_ws, size_t ws_size,
                              hipStream_t stream) {
  const float* x    = (const float*)d_in[0];
  const float* W_ih = (const float*)d_in[1];
  const float* W_hh = (const float*)d_in[2];
  const float* b_ih = (const float*)d_in[3];
  const float* b_hh = (const float*)d_in[4];
  const float* w1   = (const float*)d_in[5];
  const float* b1   = (const float*)d_in[6];
  const float* w2   = (const float*)d_in[7];
  const float* b2   = (const float*)d_in[8];
  const float* w3   = (const float*)d_in[9];
  const float* b3   = (const float*)d_in[10];
  float* out = (float*)d_out;

  char* ws = (char*)d_ws;
  _Float16* sxf = (_Float16*)ws;                          // 52,428,800 B
  _Float16* Wf  = (_Float16*)(ws + 52428800);             // 36,864 B
  _Float16* w1p = (_Float16*)(ws + 52428800 + 36864);     // 73,728 B
  _Float16* w2p = (_Float16*)(ws + 52428800 + 36864 + 73728); // 163,840 B

  hipLaunchKernelGGL(prep_kernel, dim3(536), dim3(256), 0, stream,
                     W_ih, W_hh, w1, w2, Wf, w1p, w2p);
  hipLaunchKernelGGL(gru_kernel, dim3(ZB / 16), dim3(256), 0, stream,
                     x, Wf, b_ih, b_hh, sxf);
  hipLaunchKernelGGL(mlp_kernel, dim3(Mrows / 128), dim3(256), 0, stream,
                     sxf, w1p, w2p, b1, b2, w3, b3, out);
}